// Round 15
// baseline (67.579 us; speedup 1.0000x reference)
//
#include <hip/hip_runtime.h>
#include <hip/hip_bf16.h>

// Problem: B=8192, DIM_IN=2048, DIM_OUT=512
//   hazards = relu(x @ W_h^T + b_h)            [8192,512]
//   out     = cumsum(hazards, axis=1) + (x @ W_base^T + b_base)
//
// Round 15: ALL staging via global_load_lds DMA (can't be sunk, no VGPR),
// A kept f32 in LDS (cvt on read; swizzle via pre-swizzled GLOBAL source,
// linear LDS dest). BM=64 x BN=128, 512 thr / 8 waves, LDS 74 KB ->
// 2 blocks/CU: sibling block covers the per-phase vmcnt(0)+barrier stall.
// nj in low blockIdx bits -> each XCD touches one 512 KB W quarter (L2-res).
// Cross-block cumsum via rowTotal/base ws + k_fix RMW of cols 128..511.

typedef __attribute__((ext_vector_type(8))) short  short8;
typedef __attribute__((ext_vector_type(4))) float  float4v;
typedef __attribute__((ext_vector_type(4))) float  f32x4;

#define DIN  2048
#define DOUT 512
#define NROW 8192
#define BM   64
#define BNB  128
#define NPH  (DIN / 64)   // 32 K-phases of 64

static __device__ __forceinline__ unsigned short f2bf(float f) {
  union { float f; unsigned int u; } v; v.f = f;
  unsigned int u = v.u;
  unsigned int r = (u + 0x7FFFu + ((u >> 16) & 1u)) >> 16;   // RNE
  return (unsigned short)r;
}

static __device__ __forceinline__ void dma16(const void* g, void* l) {
  __builtin_amdgcn_global_load_lds(
      (const __attribute__((address_space(1))) unsigned int*)g,
      (__attribute__((address_space(3))) unsigned int*)l, 16, 0, 0);
}

static __device__ __forceinline__ void barrier_nd() {
  asm volatile("s_waitcnt lgkmcnt(0)" ::: "memory");
  __builtin_amdgcn_s_barrier();
}

// ---- k_pack: W[512][2048] f32 -> fragment-packed bf16 ---------------------
// fragment (nt, ktp): nt = n>>4 (32), ktp = k>>5 (64).
// lane slot: n = nt*16 + (lane&15), k = ktp*32 + (lane>>4)*8 (+e)
// storage: Wp[ ((nt*64 + ktp)*64 + lane)*8 + e ] -> each frag = 1KB contig.
__global__ __launch_bounds__(256) void k_pack(const float* __restrict__ W,
                                              unsigned short* __restrict__ Wp) {
  int t    = blockIdx.x * 256 + threadIdx.x;   // 0..131071
  int lane = t & 63;
  int frag = t >> 6;
  int nt   = frag >> 6, ktp = frag & 63;
  int n = nt * 16 + (lane & 15);
  int k = ktp * 32 + (lane >> 4) * 8;
  const float* src = W + (size_t)n * DIN + k;
  float4v a = __builtin_nontemporal_load((const float4v*)src);
  float4v b = __builtin_nontemporal_load((const float4v*)(src + 4));
  unsigned short o[8] = { f2bf(a.x), f2bf(a.y), f2bf(a.z), f2bf(a.w),
                          f2bf(b.x), f2bf(b.y), f2bf(b.z), f2bf(b.w) };
  *(short8*)(Wp + (size_t)t * 8) = *(const short8*)o;
}

// ---- k_main: fused GEMM + bias + relu + partial row-scan + base -----------
// grid 512: bi = id>>2 (M-tile of 64), nj = id&3 (128-col quarter).
// 512 threads = 8 waves (2 wr x 4 wc); wave tile 32 rows x 32 cols.
// acc[mi][ni]: rows wr*32+mi*16+(lane&15), cols wc*32+ni*16+(lane>>4)*4+r.
__global__ __launch_bounds__(512, 4) void k_main(
    const float* __restrict__ x, const unsigned short* __restrict__ Wp,
    const float* __restrict__ b_h, const float* __restrict__ w_base,
    const float* __restrict__ b_base, float* __restrict__ out,
    float* __restrict__ rowTotalG, float* __restrict__ baseG) {
  __shared__ unsigned short Bf[2][16 * 512];   // 2 x 16 KB (16 frags x 1KB)
  __shared__ float Af[2][BM * 64];             // 2 x 16 KB (f32 A, src-swizzled)
  __shared__ float WbL[DIN];                   // 8 KB
  __shared__ float stripT[BM][4];
  __shared__ float baseL[BM];

  const int tid  = threadIdx.x;
  const int lane = tid & 63;
  const int wvu  = tid >> 6;       // wave 0..7
  const int wr   = wvu >> 2;       // 0..1
  const int wc   = wvu & 3;        // 0..3
  const int q    = lane >> 4;      // 0..3
  const int lm   = lane & 15;
  const int id   = blockIdx.x;
  const int bi   = id >> 2, nj = id & 3;
  const int m0   = bi * BM;
  const bool isL = (nj == 0);

  for (int i = tid; i < DIN; i += 512) WbL[i] = w_base[i];

  f32x4 acc[2][2];
  const f32x4 z4 = {0.f, 0.f, 0.f, 0.f};
#pragma unroll
  for (int mi = 0; mi < 2; ++mi)
#pragma unroll
    for (int ni = 0; ni < 2; ++ni) acc[mi][ni] = z4;

  const char* xB  = (const char*)(x + (size_t)m0 * DIN);
  const char* WpB = (const char*)Wp;
  float basePart = 0.f;

  // ---- DMA one phase: A (2 sites x 8KB, f32, global-src swizzled) +
  //                     B (2 sites x 8KB, frag-packed) ----
  auto issueDMA = [&](int p, int b) {
#pragma unroll
    for (int s = 0; s < 2; ++s) {                  // A
      const int rowb = s * 32 + wvu * 4;
      const int row  = rowb + (lane >> 4);
      const int pg   = lane & 15;
      const int lg   = pg ^ (row & 7);
      dma16(xB + (size_t)row * (DIN * 4) + p * 256 + lg * 16,
            &Af[b][rowb * 64]);
    }
#pragma unroll
    for (int s = 0; s < 2; ++s) {                  // B
      const int f  = s * 8 + wvu;                  // 0..15
      const int fg = (nj * 8 + (f >> 1)) * 64 + p * 2 + (f & 1);
      dma16(WpB + (size_t)fg * 1024 + lane * 16, &Bf[b][f * 512]);
    }
  };

  auto compute = [&](int p, int cur) {
    // B fragments: own 4, conflict-free contiguous
    short8 bfr[2][2];
#pragma unroll
    for (int ni = 0; ni < 2; ++ni)
#pragma unroll
      for (int h = 0; h < 2; ++h)
        bfr[ni][h] = *(const short8*)&Bf[cur][((wc * 2 + ni) * 2 + h) * 512 + lane * 8];
    // A fragments: f32 -> bf16 cvt (2-way bank alias only)
    short8 xf[2][2];
#pragma unroll
    for (int h = 0; h < 2; ++h)
#pragma unroll
      for (int mi = 0; mi < 2; ++mi) {
        const int row = wr * 32 + mi * 16 + lm;
        const int lg0 = (q + 4 * h) * 2;
        const float4v fa = *(const float4v*)&Af[cur][row * 64 + ((lg0 ^ (row & 7)) << 2)];
        const float4v fb = *(const float4v*)&Af[cur][row * 64 + (((lg0 + 1) ^ (row & 7)) << 2)];
        unsigned short t[8] = { f2bf(fa.x), f2bf(fa.y), f2bf(fa.z), f2bf(fa.w),
                                f2bf(fb.x), f2bf(fb.y), f2bf(fb.z), f2bf(fb.w) };
        xf[h][mi] = *(const short8*)t;
      }
#pragma unroll
    for (int h = 0; h < 2; ++h)
#pragma unroll
      for (int mi = 0; mi < 2; ++mi)
#pragma unroll
        for (int ni = 0; ni < 2; ++ni)
          acc[mi][ni] = __builtin_amdgcn_mfma_f32_16x16x32_bf16(
              bfr[ni][h], xf[h][mi], acc[mi][ni], 0, 0, 0);
    if (isL) {   // base GEMV partial: thread -> row tid>>3, 8 cols (tid&7)*8
      const int row = tid >> 3, seg = tid & 7;
      const int lg0 = seg * 2;
      const float4v fa = *(const float4v*)&Af[cur][row * 64 + ((lg0 ^ (row & 7)) << 2)];
      const float4v fb = *(const float4v*)&Af[cur][row * 64 + (((lg0 + 1) ^ (row & 7)) << 2)];
      const float4v wa = *(const float4v*)&WbL[p * 64 + seg * 8];
      const float4v wb = *(const float4v*)&WbL[p * 64 + seg * 8 + 4];
      basePart += fa.x * wa.x + fa.y * wa.y + fa.z * wa.z + fa.w * wa.w +
                  fb.x * wb.x + fb.y * wb.y + fb.z * wb.z + fb.w * wb.w;
    }
  };

  // prologue: phase 0 into buf 0
  issueDMA(0, 0);
  asm volatile("s_waitcnt vmcnt(0)" ::: "memory");
  barrier_nd();                     // A(0),B(0),WbL ready

  for (int p = 0; p < NPH; ++p) {
    const int cur = p & 1;
    if (p + 1 < NPH) issueDMA(p + 1, cur ^ 1);   // async, overlaps compute
    compute(p, cur);
    asm volatile("s_waitcnt vmcnt(0)" ::: "memory");
    barrier_nd();                   // next phase staged; sibling block covers
  }

  // ---- base reduce: 8 threads per row ----
  if (isL) {
    float s = basePart;
    s += __shfl_xor(s, 1); s += __shfl_xor(s, 2); s += __shfl_xor(s, 4);
    if ((tid & 7) == 0) baseL[tid >> 3] = s + b_base[0];
  }

  // ---- epilogue: bias + relu + scan over this wave's 32-col strip ----
  float runp[2][2][4];
  float Eq[2][2];
  float niPre[2][2];
  float Tst[2];
#pragma unroll
  for (int mi = 0; mi < 2; ++mi) {
    float run = 0.f;
#pragma unroll
    for (int ni = 0; ni < 2; ++ni) {
      float4v b4 = *(const float4v*)(b_h + nj * BNB + wc * 32 + ni * 16 + q * 4);
      f32x4 v = acc[mi][ni];
      float h0 = fmaxf(v.x + b4.x, 0.f);
      float h1 = fmaxf(v.y + b4.y, 0.f);
      float h2 = fmaxf(v.z + b4.z, 0.f);
      float h3 = fmaxf(v.w + b4.w, 0.f);
      runp[mi][ni][0] = h0;
      runp[mi][ni][1] = h0 + h1;
      runp[mi][ni][2] = h0 + h1 + h2;
      runp[mi][ni][3] = h0 + h1 + h2 + h3;
      float S = runp[mi][ni][3];
      float u1 = __shfl_up(S, 16);
      float u2 = __shfl_up(S, 32);
      float u3 = __shfl_up(S, 48);
      Eq[mi][ni] = (q >= 1 ? u1 : 0.f) + (q >= 2 ? u2 : 0.f) + (q >= 3 ? u3 : 0.f);
      float G = S + __shfl_xor(S, 16);
      G += __shfl_xor(G, 32);
      niPre[mi][ni] = run;
      run += G;
    }
    Tst[mi] = run;
  }
  if (q == 0) {
#pragma unroll
    for (int mi = 0; mi < 2; ++mi) stripT[wr * 32 + mi * 16 + lm][wc] = Tst[mi];
  }
  barrier_nd();

  // per-row totals + base to ws (for k_fix)
  if (tid < BM) {
    float4v s4 = *(const float4v*)&stripT[tid][0];
    rowTotalG[(size_t)(m0 + tid) * 4 + nj] = s4.x + s4.y + s4.z + s4.w;
    if (isL) baseG[m0 + tid] = baseL[tid];
  }

#pragma unroll
  for (int mi = 0; mi < 2; ++mi) {
    const int row = wr * 32 + mi * 16 + lm;
    float c = isL ? baseL[row] : 0.f;
    float4v s4 = *(const float4v*)&stripT[row][0];
    c += (wc > 0 ? s4.x : 0.f) + (wc > 1 ? s4.y : 0.f) + (wc > 2 ? s4.z : 0.f);
#pragma unroll
    for (int ni = 0; ni < 2; ++ni) {
      float base = c + niPre[mi][ni] + Eq[mi][ni];
      float4v o = { runp[mi][ni][0] + base, runp[mi][ni][1] + base,
                    runp[mi][ni][2] + base, runp[mi][ni][3] + base };
      __builtin_nontemporal_store(
          o, (float4v*)(out + (size_t)(m0 + row) * DOUT + nj * BNB + wc * 32 + ni * 16 + q * 4));
    }
  }
}

// ---- k_fix: out[row][128..511] += base[row] + sum of left quarters --------
__global__ __launch_bounds__(128) void k_fix(float* __restrict__ out,
                                             const float* __restrict__ rowTotal,
                                             const float* __restrict__ base) {
  const int row = blockIdx.x;
  const int j   = threadIdx.x;
  if (j >= 96) return;
  const int nj = 1 + (j >> 5);
  const float* rt = rowTotal + (size_t)row * 4;
  float pre = base[row] + rt[0];
  if (nj > 1) pre += rt[1];
  if (nj > 2) pre += rt[2];
  float4v* p = (float4v*)(out + (size_t)row * DOUT + BNB + j * 4);
  float4v v = *p;
  v.x += pre; v.y += pre; v.z += pre; v.w += pre;
  __builtin_nontemporal_store(v, p);
}

// ---------------------------------------------------------------------------
extern "C" void kernel_launch(void* const* d_in, const int* in_sizes, int n_in,
                              void* d_out, int out_size, void* d_ws, size_t ws_size,
                              hipStream_t stream) {
  const float* x   = (const float*)d_in[0];  // [8192,2048]
  const float* Wh  = (const float*)d_in[1];  // [512,2048]
  const float* bh  = (const float*)d_in[2];  // [512]
  const float* Wb0 = (const float*)d_in[3];  // [1,2048]
  const float* bb  = (const float*)d_in[4];  // [1]
  float* out = (float*)d_out;

  char* ws = (char*)d_ws;
  unsigned short* Wp = (unsigned short*)ws;                    // 2 MiB
  float* rowTotal    = (float*)(ws + 2u * 1024 * 1024);        // 128 KiB
  float* base        = (float*)(ws + 2u * 1024 * 1024 + 128u * 1024);  // 32 KiB

  k_pack<<<dim3((DOUT * DIN) / (256 * 8)), dim3(256), 0, stream>>>(Wh, Wp);
  k_main<<<dim3((NROW / BM) * (DOUT / BNB)), dim3(512), 0, stream>>>(
      x, Wp, bh, Wb0, bb, out, rowTotal, base);
  k_fix<<<dim3(NROW), dim3(128), 0, stream>>>(out, rowTotal, base);
}

// Round 16
// 65.273 us; speedup vs baseline: 1.0353x; 1.0353x over previous
//
#include <hip/hip_runtime.h>
#include <hip/hip_bf16.h>

// Problem: B=8192, DIM_IN=2048, DIM_OUT=512
//   hazards = relu(x @ W_h^T + b_h);  out = cumsum(hazards,1) + x@W_base^T + b
//
// Round 16: BYTE-MINIMAL tiling. Empirical chip ceiling: ~22 B/cyc/CU ingest
// (14 TB/s agg) across ALL 10 prior structures (matches m97/HK/hipBLASLt).
// Minimize delivered bytes: BM=BN=128 (grid 64x4=256): W 512->128 MB,
// x as precast bf16 (DMA-ready swizzled layout) 128 MB. All staging via
// global_load_lds (unsinkable), triple-buffer, counted vmcnt(2) (never 0),
// one barrier/phase. Scan carry across 4 nj-blocks via ws + k_fix.

typedef __attribute__((ext_vector_type(8))) short  short8;
typedef __attribute__((ext_vector_type(4))) float  float4v;
typedef __attribute__((ext_vector_type(4))) float  f32x4;

#define DIN  2048
#define DOUT 512
#define NROW 8192
#define BM   128
#define BN   128
#define NPH  (DIN / 64)   // 32 K-phases of 64

static __device__ __forceinline__ unsigned short f2bf(float f) {
  union { float f; unsigned int u; } v; v.f = f;
  unsigned int u = v.u;
  unsigned int r = (u + 0x7FFFu + ((u >> 16) & 1u)) >> 16;   // RNE
  return (unsigned short)r;
}
static __device__ __forceinline__ float bf2f(unsigned short u) {
  union { unsigned int u; float f; } v; v.u = ((unsigned int)u) << 16;
  return v.f;
}

static __device__ __forceinline__ void dma16(const void* g, void* l) {
  __builtin_amdgcn_global_load_lds(
      (const __attribute__((address_space(1))) unsigned int*)g,
      (__attribute__((address_space(3))) unsigned int*)l, 16, 0, 0);
}

static __device__ __forceinline__ void barrier_nd() {
  asm volatile("s_waitcnt lgkmcnt(0)" ::: "memory");
  __builtin_amdgcn_s_barrier();
}

// ---- k_pack: W[512][2048] f32 -> fragment-packed bf16 (1KB/frag) ----------
__global__ __launch_bounds__(256) void k_pack(const float* __restrict__ W,
                                              unsigned short* __restrict__ Wp) {
  int t    = blockIdx.x * 256 + threadIdx.x;   // 0..131071
  int lane = t & 63;
  int frag = t >> 6;
  int nt   = frag >> 6, ktp = frag & 63;
  int n = nt * 16 + (lane & 15);
  int k = ktp * 32 + (lane >> 4) * 8;
  const float* src = W + (size_t)n * DIN + k;
  float4v a = __builtin_nontemporal_load((const float4v*)src);
  float4v b = __builtin_nontemporal_load((const float4v*)(src + 4));
  unsigned short o[8] = { f2bf(a.x), f2bf(a.y), f2bf(a.z), f2bf(a.w),
                          f2bf(b.x), f2bf(b.y), f2bf(b.z), f2bf(b.w) };
  *(short8*)(Wp + (size_t)t * 8) = *(const short8*)o;
}

// ---- k_prex: x f32 -> Xb bf16 in DMA-ready LDS-image layout ---------------
// Xb[(bi*32+p)*8192 + site*512 + (row&7)*64 + (g^(row&7))*8] (ushort idx)
// bi=row>>7, site=(row>>3)&15, g = 8-elem granule 0..7. One block per row.
__global__ __launch_bounds__(256) void k_prex(const float* __restrict__ x,
                                              unsigned short* __restrict__ Xb) {
  const int row = blockIdx.x;
  const int t   = threadIdx.x;
  const int p   = t >> 3, g = t & 7;
  const float* src = x + (size_t)row * DIN + p * 64 + g * 8;
  float4v a = __builtin_nontemporal_load((const float4v*)src);
  float4v b = __builtin_nontemporal_load((const float4v*)(src + 4));
  unsigned short o[8] = { f2bf(a.x), f2bf(a.y), f2bf(a.z), f2bf(a.w),
                          f2bf(b.x), f2bf(b.y), f2bf(b.z), f2bf(b.w) };
  size_t off = ((size_t)(row >> 7) * 32 + p) * 8192 +
               (size_t)((row >> 3) & 15) * 512 +
               (row & 7) * 64 + ((g ^ (row & 7)) << 3);
  *(short8*)(Xb + off) = *(const short8*)o;
}

// ---- k_main: fused GEMM + bias + relu + partial row-scan + base -----------
// grid 256: swz-> bi (0..63, 128 rows), nj (0..3, 128 cols). 1024 thr = 16
// waves (4 wr x 4 wc), wave tile 32x32. All A/B staging via global_load_lds,
// 3 buffers, counted vmcnt(2), single barrier per phase.
__global__ __launch_bounds__(1024) void k_main(
    const unsigned short* __restrict__ Xb, const unsigned short* __restrict__ Wp,
    const float* __restrict__ b_h, const float* __restrict__ w_base,
    const float* __restrict__ b_base, float* __restrict__ out,
    float* __restrict__ rowTotalG, float* __restrict__ baseG) {
  __shared__ unsigned short Afs[3 * BM * 64];   // 48 KB (3 x 16 KB)
  __shared__ unsigned short Bfs[3 * 16 * 512];  // 48 KB (3 x 16 frags x 1KB)
  __shared__ float WbL[DIN];                    // 8 KB
  __shared__ float stripT[BM][4];
  __shared__ float baseL[BM];

  const int tid  = threadIdx.x;
  const int lane = tid & 63;
  const int w    = tid >> 6;       // wave 0..15
  const int wr   = w >> 2;         // 0..3 (32-row group)
  const int wc   = w & 3;          // 0..3 (32-col strip)
  const int q    = lane >> 4;      // 0..3
  const int lm   = lane & 15;

  // XCD-chunked bijective swizzle: 8 chunks of 32; bj fastest within chunk so
  // the 4 nj-sharers of an A-panel co-reside on one XCD (L2 x-reuse).
  const int id  = blockIdx.x;
  const int swz = ((id & 7) << 5) | (id >> 3);
  const int bi  = swz >> 2;        // 0..63
  const int nj  = swz & 3;         // 0..3
  const int m0  = bi * BM;
  const bool isL = (nj == 0);

  if (isL) {
    for (int i = tid; i < DIN; i += 1024) WbL[i] = w_base[i];
  }

  f32x4 acc[2][2];
  const f32x4 z4 = {0.f, 0.f, 0.f, 0.f};
#pragma unroll
  for (int mi = 0; mi < 2; ++mi)
#pragma unroll
    for (int ni = 0; ni < 2; ++ni) acc[mi][ni] = z4;

  const char* XbB = (const char*)Xb + (size_t)bi * 32 * 16384;  // A panel
  const char* WpB = (const char*)Wp;
  float basePart = 0.f;

  // one A-site (1KB, 8 rows) + one B-frag (1KB) per wave per phase
  auto issue = [&](int p, int b) {
    dma16(XbB + (size_t)p * 16384 + w * 1024 + lane * 16,
          &Afs[b * 8192 + w * 512]);
    const int fg = (nj * 8 + (w >> 1)) * 64 + p * 2 + (w & 1);
    dma16(WpB + (size_t)fg * 1024 + lane * 16,
          &Bfs[b * 8192 + w * 512]);
  };

  auto compute = [&](int p, int b) {
    const unsigned short* Af = &Afs[b * 8192];
    const unsigned short* Bf = &Bfs[b * 8192];
    short8 xf[2][2], bfr[2][2];
#pragma unroll
    for (int h = 0; h < 2; ++h)
#pragma unroll
      for (int mi = 0; mi < 2; ++mi) {
        const int row = wr * 32 + mi * 16 + lm;
        const int g   = q + 4 * h;
        xf[h][mi] = *(const short8*)&Af[row * 64 + ((g ^ (row & 7)) << 3)];
      }
#pragma unroll
    for (int ni = 0; ni < 2; ++ni)
#pragma unroll
      for (int h = 0; h < 2; ++h)
        bfr[ni][h] = *(const short8*)&Bf[((wc * 2 + ni) * 2 + h) * 512 + lane * 8];
#pragma unroll
    for (int h = 0; h < 2; ++h)
#pragma unroll
      for (int mi = 0; mi < 2; ++mi)
#pragma unroll
        for (int ni = 0; ni < 2; ++ni)
          acc[mi][ni] = __builtin_amdgcn_mfma_f32_16x16x32_bf16(
              bfr[ni][h], xf[h][mi], acc[mi][ni], 0, 0, 0);
    if (isL) {  // base GEMV partial from A tile (8 thr/row, 8 elems each)
      const int row = tid >> 3, seg = tid & 7;
      const short8 v = *(const short8*)&Af[row * 64 + ((seg ^ (row & 7)) << 3)];
#pragma unroll
      for (int e = 0; e < 8; ++e)
        basePart += bf2f((unsigned short)v[e]) * WbL[p * 64 + seg * 8 + e];
    }
  };

  // prologue: WbL (compiler-drained), then phases 0,1 in flight; wait own p0.
  issue(0, 0);
  issue(1, 1);
  asm volatile("s_waitcnt vmcnt(2)" ::: "memory");   // p0 + WbL landed
  barrier_nd();

  for (int p = 0; p < NPH; ++p) {
    const int cur = p % 3;
    compute(p, cur);
    if (p + 2 < NPH) {
      issue(p + 2, (p + 2) % 3);
      asm volatile("s_waitcnt vmcnt(2)" ::: "memory");  // own p+1 landed
    } else {
      asm volatile("s_waitcnt vmcnt(0)" ::: "memory");  // tail drain
    }
    barrier_nd();
  }

  // ---- base reduce: 8 consecutive threads share a row ----
  if (isL) {
    float s = basePart;
    s += __shfl_xor(s, 1); s += __shfl_xor(s, 2); s += __shfl_xor(s, 4);
    if ((tid & 7) == 0) baseL[tid >> 3] = s + b_base[0];
  }

  // ---- epilogue: bias + relu + scan over this wave's 32-col strip ----
  float runp[2][2][4];
  float Eq[2][2];
  float niPre[2][2];
  float Tst[2];
#pragma unroll
  for (int mi = 0; mi < 2; ++mi) {
    float run = 0.f;
#pragma unroll
    for (int ni = 0; ni < 2; ++ni) {
      float4v b4 = *(const float4v*)(b_h + nj * BN + wc * 32 + ni * 16 + q * 4);
      f32x4 v = acc[mi][ni];
      float h0 = fmaxf(v.x + b4.x, 0.f);
      float h1 = fmaxf(v.y + b4.y, 0.f);
      float h2 = fmaxf(v.z + b4.z, 0.f);
      float h3 = fmaxf(v.w + b4.w, 0.f);
      runp[mi][ni][0] = h0;
      runp[mi][ni][1] = h0 + h1;
      runp[mi][ni][2] = h0 + h1 + h2;
      runp[mi][ni][3] = h0 + h1 + h2 + h3;
      float S = runp[mi][ni][3];
      float u1 = __shfl_up(S, 16);
      float u2 = __shfl_up(S, 32);
      float u3 = __shfl_up(S, 48);
      Eq[mi][ni] = (q >= 1 ? u1 : 0.f) + (q >= 2 ? u2 : 0.f) + (q >= 3 ? u3 : 0.f);
      float G = S + __shfl_xor(S, 16);
      G += __shfl_xor(G, 32);
      niPre[mi][ni] = run;
      run += G;
    }
    Tst[mi] = run;
  }
  if (q == 0) {
#pragma unroll
    for (int mi = 0; mi < 2; ++mi) stripT[wr * 32 + mi * 16 + lm][wc] = Tst[mi];
  }
  barrier_nd();

  if (tid < BM) {
    float4v s4 = *(const float4v*)&stripT[tid][0];
    rowTotalG[(size_t)(m0 + tid) * 4 + nj] = s4.x + s4.y + s4.z + s4.w;
    if (isL) baseG[m0 + tid] = baseL[tid];
  }

#pragma unroll
  for (int mi = 0; mi < 2; ++mi) {
    const int row = wr * 32 + mi * 16 + lm;
    float c = isL ? baseL[row] : 0.f;
    float4v s4 = *(const float4v*)&stripT[row][0];
    c += (wc > 0 ? s4.x : 0.f) + (wc > 1 ? s4.y : 0.f) + (wc > 2 ? s4.z : 0.f);
#pragma unroll
    for (int ni = 0; ni < 2; ++ni) {
      float base = c + niPre[mi][ni] + Eq[mi][ni];
      float4v o = { runp[mi][ni][0] + base, runp[mi][ni][1] + base,
                    runp[mi][ni][2] + base, runp[mi][ni][3] + base };
      *(float4v*)(out + (size_t)(m0 + row) * DOUT + nj * BN + wc * 32 + ni * 16 + q * 4) = o;
    }
  }
}

// ---- k_fix: out[row][128..511] += base[row] + sum of left quarters --------
__global__ __launch_bounds__(128) void k_fix(float* __restrict__ out,
                                             const float* __restrict__ rowTotal,
                                             const float* __restrict__ base) {
  const int row = blockIdx.x;
  const int j   = threadIdx.x;
  if (j >= 96) return;
  const int s = j >> 5;                 // 0,1,2 -> quarters 1,2,3
  const float* rt = rowTotal + (size_t)row * 4;
  float pre = base[row] + rt[0];
  if (s >= 1) pre += rt[1];
  if (s >= 2) pre += rt[2];
  float4v* p = (float4v*)(out + (size_t)row * DOUT + 128 + j * 4);
  float4v v = *p;
  v.x += pre; v.y += pre; v.z += pre; v.w += pre;
  __builtin_nontemporal_store(v, p);
}

// ---------------------------------------------------------------------------
extern "C" void kernel_launch(void* const* d_in, const int* in_sizes, int n_in,
                              void* d_out, int out_size, void* d_ws, size_t ws_size,
                              hipStream_t stream) {
  const float* x   = (const float*)d_in[0];  // [8192,2048]
  const float* Wh  = (const float*)d_in[1];  // [512,2048]
  const float* bh  = (const float*)d_in[2];  // [512]
  const float* Wb0 = (const float*)d_in[3];  // [1,2048]
  const float* bb  = (const float*)d_in[4];  // [1]
  float* out = (float*)d_out;

  char* ws = (char*)d_ws;
  const size_t MB = 1024u * 1024u;
  unsigned short* Wp = (unsigned short*)ws;              // 2 MiB
  unsigned short* Xb = (unsigned short*)(ws + 2 * MB);   // 32 MiB
  float* rowTotal    = (float*)(ws + 34 * MB);           // 128 KiB
  float* baseG       = (float*)(ws + 34 * MB + 256u * 1024u);  // 32 KiB

  k_pack<<<dim3((DOUT * DIN) / (256 * 8)), dim3(256), 0, stream>>>(Wh, Wp);
  k_prex<<<dim3(NROW), dim3(256), 0, stream>>>(x, Xb);
  k_main<<<dim3((NROW / BM) * (DOUT / BN)), dim3(1024), 0, stream>>>(
      Xb, Wp, bh, Wb0, bb, out, rowTotal, baseG);
  k_fix<<<dim3(NROW), dim3(128), 0, stream>>>(out, rowTotal, baseG);
}